// Round 4
// baseline (349.876 us; speedup 1.0000x reference)
//
#include <hip/hip_runtime.h>
#include <hip/hip_bf16.h>

#define S_LEN 2048
#define BATCH 2
#define DMODEL 1024
#define NHEAD 16
#define DHEAD 64
#define WINDOW 256

typedef unsigned short u16;
typedef __attribute__((ext_vector_type(8))) short bf16x8;
typedef __attribute__((ext_vector_type(4))) float f32x4;

__device__ __forceinline__ float b2f(u16 u) {
    union { unsigned int i; float f; } x; x.i = ((unsigned int)u) << 16; return x.f;
}
__device__ __forceinline__ u16 f2b(float f) {
    union { float f; unsigned int i; } x; x.f = f;
    unsigned int r = x.i + 0x7fffu + ((x.i >> 16) & 1u);
    return (u16)(r >> 16);
}
// load 8 consecutive fp32, round-to-nearest-even to bf16x8
__device__ __forceinline__ bf16x8 ld8f(const float* __restrict__ p) {
    bf16x8 r;
    #pragma unroll
    for (int i = 0; i < 8; i++) r[i] = (short)f2b(p[i]);
    return r;
}

// C[m][n] = sum_k A[m][k]*W[n][k] + bias[n];  A,W,bias fp32; C bf16 (staging).
__global__ __launch_bounds__(256) void gemm_f32in(
    const float* __restrict__ A, const float* __restrict__ W,
    const float* __restrict__ bias, u16* __restrict__ C,
    int M, int N, int K)
{
    const int lane = threadIdx.x & 63;
    const int wave = threadIdx.x >> 6;
    const int r15 = lane & 15, g = lane >> 4;
    const int m0 = blockIdx.x * 128 + (wave >> 1) * 64;
    const int n0 = blockIdx.y * 128 + (wave & 1) * 64;
    const float* a0 = A + (size_t)(m0 + r15) * K + g * 8;
    const float* w0 = W + (size_t)(n0 + r15) * K + g * 8;
    f32x4 acc[4][4] = {};
    for (int k = 0; k < K; k += 32) {
        bf16x8 af[4], bf[4];
        #pragma unroll
        for (int mi = 0; mi < 4; mi++) af[mi] = ld8f(a0 + (size_t)mi * 16 * K + k);
        #pragma unroll
        for (int ni = 0; ni < 4; ni++) bf[ni] = ld8f(w0 + (size_t)ni * 16 * K + k);
        #pragma unroll
        for (int mi = 0; mi < 4; mi++)
            #pragma unroll
            for (int ni = 0; ni < 4; ni++)
                acc[mi][ni] = __builtin_amdgcn_mfma_f32_16x16x32_bf16(
                    af[mi], bf[ni], acc[mi][ni], 0, 0, 0);
    }
    #pragma unroll
    for (int ni = 0; ni < 4; ni++) {
        const int col = n0 + ni * 16 + r15;
        const float bv = bias[col];
        #pragma unroll
        for (int mi = 0; mi < 4; mi++)
            #pragma unroll
            for (int r = 0; r < 4; r++) {
                const int row = m0 + mi * 16 + g * 4 + r;
                C[(size_t)row * N + col] = f2b(acc[mi][ni][r] + bv);
            }
    }
}

// Final GEMM: A bf16 (attention out), W/bias fp32, C = FP32 (d_out dtype).
__global__ __launch_bounds__(256) void gemm_bf16A_f32out(
    const u16* __restrict__ A, const float* __restrict__ W,
    const float* __restrict__ bias, float* __restrict__ C,
    int M, int N, int K)
{
    const int lane = threadIdx.x & 63;
    const int wave = threadIdx.x >> 6;
    const int r15 = lane & 15, g = lane >> 4;
    const int m0 = blockIdx.x * 128 + (wave >> 1) * 64;
    const int n0 = blockIdx.y * 128 + (wave & 1) * 64;
    const u16* a0 = A + (size_t)(m0 + r15) * K + g * 8;
    const float* w0 = W + (size_t)(n0 + r15) * K + g * 8;
    f32x4 acc[4][4] = {};
    for (int k = 0; k < K; k += 32) {
        bf16x8 af[4], bf[4];
        #pragma unroll
        for (int mi = 0; mi < 4; mi++)
            af[mi] = *reinterpret_cast<const bf16x8*>(a0 + (size_t)mi * 16 * K + k);
        #pragma unroll
        for (int ni = 0; ni < 4; ni++) bf[ni] = ld8f(w0 + (size_t)ni * 16 * K + k);
        #pragma unroll
        for (int mi = 0; mi < 4; mi++)
            #pragma unroll
            for (int ni = 0; ni < 4; ni++)
                acc[mi][ni] = __builtin_amdgcn_mfma_f32_16x16x32_bf16(
                    af[mi], bf[ni], acc[mi][ni], 0, 0, 0);
    }
    #pragma unroll
    for (int ni = 0; ni < 4; ni++) {
        const int col = n0 + ni * 16 + r15;
        const float bv = bias[col];
        #pragma unroll
        for (int mi = 0; mi < 4; mi++)
            #pragma unroll
            for (int r = 0; r < 4; r++) {
                const int row = m0 + mi * 16 + g * 4 + r;
                C[(size_t)row * N + col] = acc[mi][ni][r] + bv;
            }
    }
}

// Fused Q-projection + sliding-window attention. One wave per (b,h,16-query tile).
// ALL MFMAs are mfma_f32_16x16x32_bf16. 32 keys per step; swapped QK (S^T);
// PV B-fragment assembled from C-layout via __shfl.
__global__ __launch_bounds__(256) void attn_fused(
    const float* __restrict__ x, const float* __restrict__ Wq,
    const float* __restrict__ bq, const u16* __restrict__ Kb,
    const u16* __restrict__ Vb, const float* __restrict__ beta,
    u16* __restrict__ O)
{
    __shared__ u16 qlds[4][16][64];
    const int lane = threadIdx.x & 63;
    const int wave = threadIdx.x >> 6;
    const int wid = blockIdx.x * 4 + wave;                   // 0..4095
    const int qt = wid & (S_LEN / 16 - 1);
    const int h  = (wid >> 7) & (NHEAD - 1);
    const int b  = wid >> 11;
    const int qstart = qt * 16;
    const int r15 = lane & 15, g = lane >> 4;
    const int i_glob = qstart + r15;

    // ---- Stage 1: q[16 queries][64 dh] = x @ Wq_head^T + bq, via MFMA ----
    f32x4 qa[4] = {};
    const float* xrow = x + ((size_t)i_glob * BATCH + b) * DMODEL;
    const float* wqb  = Wq + (size_t)(h * DHEAD) * DMODEL;
    for (int k = 0; k < DMODEL; k += 32) {
        const bf16x8 xf = ld8f(xrow + k + g * 8);
        #pragma unroll
        for (int c = 0; c < 4; c++) {
            const bf16x8 wf = ld8f(wqb + (size_t)(c * 16 + r15) * DMODEL + k + g * 8);
            qa[c] = __builtin_amdgcn_mfma_f32_16x16x32_bf16(wf, xf, qa[c], 0, 0, 0);
        }
    }
    #pragma unroll
    for (int c = 0; c < 4; c++)
        #pragma unroll
        for (int j = 0; j < 4; j++) {
            const int dh = c * 16 + g * 4 + j;
            qlds[wave][r15][dh] = f2b(qa[c][j] + bq[h * DHEAD + dh]);
        }
    __syncthreads();
    const bf16x8 qf0 = *reinterpret_cast<const bf16x8*>(&qlds[wave][r15][g * 8]);
    const bf16x8 qf1 = *reinterpret_cast<const bf16x8*>(&qlds[wave][r15][32 + g * 8]);

    // ---- Stage 2: flash sliding-window attention, 32 keys/step ----
    const float scale = 1.0f / (8.0f * __expf(beta[h]));
    float m = -1e30f, lsum = 0.0f;
    f32x4 o[4] = {};
    const int kt0 = (qstart >= WINDOW) ? (qstart - WINDOW) : 0;

    for (int kt = kt0; kt <= kt0 + WINDOW; kt += 32) {
        f32x4 st0 = {0.f, 0.f, 0.f, 0.f}, st1 = {0.f, 0.f, 0.f, 0.f};
        {
            const int kr = min(kt + r15, S_LEN - 1);
            const u16* kp = Kb + ((size_t)kr * BATCH + b) * DMODEL + h * DHEAD;
            const bf16x8 ka = *reinterpret_cast<const bf16x8*>(kp + g * 8);
            const bf16x8 kb2 = *reinterpret_cast<const bf16x8*>(kp + 32 + g * 8);
            st0 = __builtin_amdgcn_mfma_f32_16x16x32_bf16(ka, qf0, st0, 0, 0, 0);
            st0 = __builtin_amdgcn_mfma_f32_16x16x32_bf16(kb2, qf1, st0, 0, 0, 0);
        }
        {
            const int kr = min(kt + 16 + r15, S_LEN - 1);
            const u16* kp = Kb + ((size_t)kr * BATCH + b) * DMODEL + h * DHEAD;
            const bf16x8 ka = *reinterpret_cast<const bf16x8*>(kp + g * 8);
            const bf16x8 kb2 = *reinterpret_cast<const bf16x8*>(kp + 32 + g * 8);
            st1 = __builtin_amdgcn_mfma_f32_16x16x32_bf16(ka, qf0, st1, 0, 0, 0);
            st1 = __builtin_amdgcn_mfma_f32_16x16x32_bf16(kb2, qf1, st1, 0, 0, 0);
        }

        float p0[4], p1[4];
        #pragma unroll
        for (int r = 0; r < 4; r++) {
            const int j0 = kt + g * 4 + r;
            const int d0 = i_glob - j0;
            p0[r] = (d0 < 0 || d0 >= WINDOW) ? -3e38f : st0[r] * scale;
            const int j1 = kt + 16 + g * 4 + r;
            const int d1 = i_glob - j1;
            p1[r] = (d1 < 0 || d1 >= WINDOW) ? -3e38f : st1[r] * scale;
        }
        float pmax = -3e38f;
        #pragma unroll
        for (int r = 0; r < 4; r++) pmax = fmaxf(pmax, fmaxf(p0[r], p1[r]));
        pmax = fmaxf(pmax, __shfl_xor(pmax, 16));
        pmax = fmaxf(pmax, __shfl_xor(pmax, 32));
        const float mnew = fmaxf(m, pmax);
        const float alpha = __expf(m - mnew);
        float psum = 0.0f;
        #pragma unroll
        for (int r = 0; r < 4; r++) {
            p0[r] = __expf(p0[r] - mnew);
            p1[r] = __expf(p1[r] - mnew);
            psum += p0[r] + p1[r];
        }
        psum += __shfl_xor(psum, 16);
        psum += __shfl_xor(psum, 32);
        lsum = lsum * alpha + psum;
        m = mnew;
        #pragma unroll
        for (int c = 0; c < 4; c++)
            #pragma unroll
            for (int r = 0; r < 4; r++) o[c][r] *= alpha;

        // assemble P^T B-fragment: reg i <- key kt + 8g + i
        bf16x8 pf;
        const int base = ((g & 1) * 2) * 16 + r15;
        #pragma unroll
        for (int i = 0; i < 8; i++) {
            const int src = base + (i >> 2) * 16;
            const float v0 = __shfl(p0[i & 3], src);
            const float v1 = __shfl(p1[i & 3], src);
            pf[i] = (short)f2b((g < 2) ? v0 : v1);
        }

        // PV: o^T[dh][q] += V^T · P^T over 32 keys
        #pragma unroll
        for (int c = 0; c < 4; c++) {
            bf16x8 vf;
            #pragma unroll
            for (int i = 0; i < 8; i++) {
                const int vrow = min(kt + g * 8 + i, S_LEN - 1);
                vf[i] = (short)Vb[((size_t)vrow * BATCH + b) * DMODEL + h * DHEAD + c * 16 + r15];
            }
            o[c] = __builtin_amdgcn_mfma_f32_16x16x32_bf16(vf, pf, o[c], 0, 0, 0);
        }
    }

    const float inv = 1.0f / lsum;
    #pragma unroll
    for (int c = 0; c < 4; c++)
        #pragma unroll
        for (int r = 0; r < 4; r++) {
            const int dh = c * 16 + g * 4 + r;
            O[((size_t)i_glob * BATCH + b) * DMODEL + h * DHEAD + dh] = f2b(o[c][r] * inv);
        }
}

extern "C" void kernel_launch(void* const* d_in, const int* in_sizes, int n_in,
                              void* d_out, int out_size, void* d_ws, size_t ws_size,
                              hipStream_t stream) {
    const float* x    = (const float*)d_in[0];
    const float* Wq   = (const float*)d_in[1];
    const float* bq   = (const float*)d_in[2];
    const float* Wk   = (const float*)d_in[3];
    const float* bk   = (const float*)d_in[4];
    const float* Wv   = (const float*)d_in[5];
    const float* bv   = (const float*)d_in[6];
    const float* Wo   = (const float*)d_in[7];
    const float* bo   = (const float*)d_in[8];
    const float* beta = (const float*)d_in[9];
    float* out = (float*)d_out;            // reference output dtype = fp32
    u16* ws  = (u16*)d_ws;

    const size_t MAT = (size_t)S_LEN * BATCH * DMODEL;  // 4M elems
    u16* kbuf = (u16*)d_out;  // K staged bf16 in first 8MB of the 16MB d_out
    u16* vbuf = ws;           // 8 MB
    u16* abuf = ws + MAT;     // 8 MB  (total ws use: 16 MB)

    const int M = S_LEN * BATCH;           // 4096
    dim3 gg(M / 128, DMODEL / 128);        // (32, 8)

    gemm_f32in<<<gg, 256, 0, stream>>>(x, Wk, bk, kbuf, M, DMODEL, DMODEL);
    gemm_f32in<<<gg, 256, 0, stream>>>(x, Wv, bv, vbuf, M, DMODEL, DMODEL);

    const int nwaves = BATCH * NHEAD * (S_LEN / 16);   // 4096
    attn_fused<<<nwaves / 4, 256, 0, stream>>>(x, Wq, bq, kbuf, vbuf, beta, abuf);

    gemm_bf16A_f32out<<<gg, 256, 0, stream>>>(abuf, Wo, bo, out, M, DMODEL, DMODEL);
}